// Round 7
// baseline (470.555 us; speedup 1.0000x reference)
//
#include <hip/hip_runtime.h>
#include <hip/hip_cooperative_groups.h>
#include <hip/hip_bf16.h>

namespace cg = cooperative_groups;

#define NN 50000
#define NE 800000
#define HID 128
#define ROWD 68           // x1 LDS pitch in dwords
#define APITCH 136        // node-phase A-tile pitch in bf16 elems
#define NT_NODE 1563      // ceil(NN/32)
#define NT_EDGE 12500     // NE/64
#define N1 (32*128*8)     // W1p shorts
#define N2 (16*128*8)     // W2p shorts
#define OUTQ 37500        // out float4s (150000/4)
#define SMEM_BYTES 19456

typedef float f32x4 __attribute__((ext_vector_type(4)));
typedef short s16x8 __attribute__((ext_vector_type(8)));
typedef unsigned int u32;

__device__ __forceinline__ unsigned short f2bf(float x) {   // RNE
    u32 u = __float_as_uint(x);
    u32 r = (u + 0x7FFFu + ((u >> 16) & 1u)) >> 16;
    return (unsigned short)r;
}
__device__ __forceinline__ float silu_f(float v) {
    float e = __expf(-v);
    return v * __builtin_amdgcn_rcpf(1.f + e);
}
__device__ __forceinline__ u32 pack2bf(float lo, float hi) {
    return __builtin_amdgcn_perm(__float_as_uint(hi), __float_as_uint(lo), 0x07060302u);
}
__device__ __forceinline__ u32 fuse_silu_pack(u32 a, u32 b, float ea, float wlo, float whi) {
    float xlo = __uint_as_float(a << 16) + __uint_as_float(b << 16) + ea * wlo;
    float xhi = __uint_as_float(a & 0xFFFF0000u) + __uint_as_float(b & 0xFFFF0000u) + ea * whi;
    return pack2bf(silu_f(xlo), silu_f(xhi));
}

// ---------------- phase 0: weight repack + out zero ----------------
__device__ void phase_prep(int gid, int gstride,
                           const float* __restrict__ W1, const float* __restrict__ W2,
                           unsigned short* __restrict__ W1p, unsigned short* __restrict__ W2p,
                           float4* __restrict__ outz) {
    for (int idx = gid; idx < N1 + N2 + OUTQ; idx += gstride) {
        if (idx < N1) {
            int kblk = idx >> 10;
            int rem  = idx & 1023;
            int n    = rem >> 3;
            int kin  = rem & 7;
            W1p[idx] = f2bf(W1[(kblk * 8 + kin) * HID + n]);
        } else if (idx < N1 + N2) {
            int jj   = idx - N1;
            int kblk = jj >> 10;
            int rem  = jj & 1023;
            int n    = rem >> 3;
            int kin  = rem & 7;
            int p    = kblk * 8 + kin;
            int tt   = p >> 1;
            int srow = 32 * (tt >> 4) + (tt & 15) + 16 * (p & 1);
            W2p[jj] = f2bf(W2[srow * HID + n]);
        } else {
            outz[idx - N1 - N2] = float4{0.f, 0.f, 0.f, 0.f};
        }
    }
}

// ---------------- phase 1: Pa = h@W1a + b1, Pb = h@W1b (sigma-paired bf16) ----------------
__device__ void phase_node(unsigned char* smem, const float* __restrict__ h,
                           const unsigned short* __restrict__ W1p,
                           const float* __restrict__ b1,
                           u32* __restrict__ Pa, u32* __restrict__ Pb) {
    unsigned short* s_a = (unsigned short*)smem;   // 32 * APITCH shorts = 8704 B
    const int tid  = threadIdx.x;
    const int lane = tid & 63;
    const int w    = tid >> 6;
    const int q    = lane >> 4;
    const int c16  = lane & 15;
    const int n0   = w * 32 + c16;
    const float b1lo = b1[n0], b1hi = b1[n0 + 16];
    const int d = w * 16 + c16;

    for (int tn = blockIdx.x; tn < NT_NODE; tn += gridDim.x) {
        const int m0 = tn * 32;
        #pragma unroll
        for (int it = 0; it < 4; ++it) {
            int chunk = it * 256 + tid;          // 0..1023 float4 chunks
            int r = chunk >> 5, cc = chunk & 31;
            int row = m0 + r;
            float4 v = {0.f, 0.f, 0.f, 0.f};
            if (row < NN) v = *(const float4*)(h + (size_t)row * HID + cc * 4);
            uint2 pk;
            pk.x = ((u32)f2bf(v.x)) | ((u32)f2bf(v.y) << 16);
            pk.y = ((u32)f2bf(v.z)) | ((u32)f2bf(v.w) << 16);
            *(uint2*)&s_a[r * APITCH + cc * 4] = pk;
        }
        __syncthreads();

        f32x4 aA[2][2], aB[2][2];
        #pragma unroll
        for (int mt = 0; mt < 2; ++mt) {
            aA[mt][0] = f32x4{0.f,0.f,0.f,0.f}; aA[mt][1] = f32x4{0.f,0.f,0.f,0.f};
            aB[mt][0] = f32x4{0.f,0.f,0.f,0.f}; aB[mt][1] = f32x4{0.f,0.f,0.f,0.f};
        }
        #pragma unroll
        for (int ks = 0; ks < 4; ++ks) {
            s16x8 afr[2];
            afr[0] = *(const s16x8*)&s_a[(c16) * APITCH + ks * 32 + q * 8];
            afr[1] = *(const s16x8*)&s_a[(16 + c16) * APITCH + ks * 32 + q * 8];
            int ka = ks * 4 + q;
            int kb = 16 + ks * 4 + q;
            s16x8 ba0 = *(const s16x8*)(W1p + (size_t)(ka * HID + n0) * 8);
            s16x8 ba1 = *(const s16x8*)(W1p + (size_t)(ka * HID + n0 + 16) * 8);
            s16x8 bb0 = *(const s16x8*)(W1p + (size_t)(kb * HID + n0) * 8);
            s16x8 bb1 = *(const s16x8*)(W1p + (size_t)(kb * HID + n0 + 16) * 8);
            #pragma unroll
            for (int mt = 0; mt < 2; ++mt) {
                aA[mt][0] = __builtin_amdgcn_mfma_f32_16x16x32_bf16(afr[mt], ba0, aA[mt][0], 0, 0, 0);
                aA[mt][1] = __builtin_amdgcn_mfma_f32_16x16x32_bf16(afr[mt], ba1, aA[mt][1], 0, 0, 0);
                aB[mt][0] = __builtin_amdgcn_mfma_f32_16x16x32_bf16(afr[mt], bb0, aB[mt][0], 0, 0, 0);
                aB[mt][1] = __builtin_amdgcn_mfma_f32_16x16x32_bf16(afr[mt], bb1, aB[mt][1], 0, 0, 0);
            }
        }
        #pragma unroll
        for (int mt = 0; mt < 2; ++mt) {
            #pragma unroll
            for (int r = 0; r < 4; ++r) {
                int m = mt * 16 + q * 4 + r;     // C/D: col=lane&15, row=quad*4+reg
                int row = m0 + m;
                if (row < NN) {
                    Pa[(size_t)row * 64 + d] = pack2bf(aA[mt][0][r] + b1lo, aA[mt][1][r] + b1hi);
                    Pb[(size_t)row * 64 + d] = pack2bf(aB[mt][0][r], aB[mt][1][r]);
                }
            }
        }
        __syncthreads();   // s_a reuse next tile
    }
}

// ---------------- phase 2: edges (R4 structure, 2 barriers/tile) ----------------
__device__ void phase_edge(unsigned char* smem,
                           const u32* __restrict__ Pa, const u32* __restrict__ Pb,
                           const int* __restrict__ edge_index,
                           const float* __restrict__ coord_diff,
                           const float* __restrict__ edge_attr,
                           const float* __restrict__ edge_mask,
                           const unsigned short* __restrict__ W2p,
                           const float* __restrict__ W1,
                           const float* __restrict__ b2, const float* __restrict__ W3,
                           float* __restrict__ agg) {
    u32*   s_x1  = (u32*)smem;                    // 64*ROWD dwords = 17408 B
    float* s_phi = (float*)(smem + 17408);        // 256 floats = 1024 B

    const int tid  = threadIdx.x;
    const int lane = tid & 63;
    const int w    = tid >> 6;
    const int q    = lane >> 4;
    const int c16  = lane & 15;
    const int n0   = w * 32 + c16;

    // fuse constants for this thread's dword group c = tid&15
    const int c = tid & 15;
    const float* W1r = W1 + 256 * HID;
    float w1rlo[4], w1rhi[4];
    #pragma unroll
    for (int i = 0; i < 4; ++i) {
        int dd = c * 4 + i;
        int cl = 32 * (dd >> 4) + (dd & 15);
        w1rlo[i] = W1r[cl];
        w1rhi[i] = W1r[cl + 16];
    }
    const float b2lo = b2[n0], b2hi = b2[n0 + 16];
    const float w3lo = W3[n0], w3hi = W3[n0 + 16];

    for (int te = blockIdx.x; te < NT_EDGE; te += gridDim.x) {
        const int e0 = te * 64;

        // gather Pa[row]+Pb[col], fuse ea*w1r + silu, write x1 tile
        #pragma unroll
        for (int it = 0; it < 4; ++it) {
            int m  = it * 16 + (tid >> 4);
            int e  = e0 + m;
            int ri = edge_index[e];
            int ci = edge_index[NE + e];
            float ea = edge_attr[e];
            uint4 pa = *(const uint4*)(Pa + (size_t)ri * 64 + c * 4);
            uint4 pb = *(const uint4*)(Pb + (size_t)ci * 64 + c * 4);
            uint4 o;
            o.x = fuse_silu_pack(pa.x, pb.x, ea, w1rlo[0], w1rhi[0]);
            o.y = fuse_silu_pack(pa.y, pb.y, ea, w1rlo[1], w1rhi[1]);
            o.z = fuse_silu_pack(pa.z, pb.z, ea, w1rlo[2], w1rhi[2]);
            o.w = fuse_silu_pack(pa.w, pb.w, ea, w1rlo[3], w1rhi[3]);
            *(uint4*)&s_x1[m * ROWD + c * 4] = o;
        }
        __syncthreads();   // B_x1

        // layer 2: [64,128] @ W2p (sigma-K)
        f32x4 acc2[4][2];
        #pragma unroll
        for (int mt = 0; mt < 4; ++mt) {
            acc2[mt][0] = f32x4{0.f,0.f,0.f,0.f};
            acc2[mt][1] = f32x4{0.f,0.f,0.f,0.f};
        }
        #pragma unroll
        for (int ks = 0; ks < 4; ++ks) {
            int kblk = ks * 4 + q;
            s16x8 b0  = *(const s16x8*)(W2p + (size_t)(kblk * HID + n0) * 8);
            s16x8 b1f = *(const s16x8*)(W2p + (size_t)(kblk * HID + n0 + 16) * 8);
            #pragma unroll
            for (int mt = 0; mt < 4; ++mt) {
                s16x8 afr = *(const s16x8*)&s_x1[(mt * 16 + c16) * ROWD + ks * 16 + q * 4];
                acc2[mt][0] = __builtin_amdgcn_mfma_f32_16x16x32_bf16(afr, b0,  acc2[mt][0], 0, 0, 0);
                acc2[mt][1] = __builtin_amdgcn_mfma_f32_16x16x32_bf16(afr, b1f, acc2[mt][1], 0, 0, 0);
            }
        }

        // layer 3: phi = sum_n silu(x2+b2)*W3
        #pragma unroll
        for (int mt = 0; mt < 4; ++mt) {
            float pr[4];
            #pragma unroll
            for (int r = 0; r < 4; ++r) {
                float s0 = silu_f(acc2[mt][0][r] + b2lo);
                float s1 = silu_f(acc2[mt][1][r] + b2hi);
                pr[r] = fmaf(s0, w3lo, fmaf(s1, w3hi, 0.f));
            }
            #pragma unroll
            for (int off = 8; off >= 1; off >>= 1) {
                #pragma unroll
                for (int r = 0; r < 4; ++r) pr[r] += __shfl_xor(pr[r], off);
            }
            if (c16 == 0) {
                #pragma unroll
                for (int r = 0; r < 4; ++r)
                    s_phi[(mt * 16 + q * 4 + r) * 4 + w] = pr[r];
            }
        }
        __syncthreads();   // B_phi (also releases s_x1 for next tile)

        if (tid < 64) {
            int e = e0 + tid;
            float phi = s_phi[tid * 4 + 0] + s_phi[tid * 4 + 1]
                      + s_phi[tid * 4 + 2] + s_phi[tid * 4 + 3];
            float scale = phi * edge_mask[e];
            int r = edge_index[e];
            atomicAdd(&agg[r * 3 + 0], coord_diff[e * 3 + 0] * scale);
            atomicAdd(&agg[r * 3 + 1], coord_diff[e * 3 + 1] * scale);
            atomicAdd(&agg[r * 3 + 2], coord_diff[e * 3 + 2] * scale);
        }
        // no end barrier: s_phi rewrite is ordered behind next tile's B_x1
    }
}

// ---------------- phase 3: finalize ----------------
__device__ void phase_fin(int gid, int gstride, const float* __restrict__ coord,
                          const float* __restrict__ node_mask, float* __restrict__ out) {
    for (int i = gid; i < NN; i += gstride) {
        float nm = node_mask[i];
        float a0 = out[i*3+0], a1 = out[i*3+1], a2 = out[i*3+2];
        out[i*3+0] = (coord[i*3+0] + a0 * 0.01f) * nm;
        out[i*3+1] = (coord[i*3+1] + a1 * 0.01f) * nm;
        out[i*3+2] = (coord[i*3+2] + a2 * 0.01f) * nm;
    }
}

// ---------------- fused cooperative kernel ----------------
__global__ __launch_bounds__(256, 5) void fused_all(
        const float* h, const int* edge_index, const float* coord,
        const float* coord_diff, const float* edge_attr,
        const float* node_mask, const float* edge_mask,
        const float* W1, const float* b1, const float* W2,
        const float* b2, const float* W3,
        unsigned short* W1p, unsigned short* W2p, u32* Pa, u32* Pb, float* out) {
    __shared__ __align__(16) unsigned char smem[SMEM_BYTES];
    const int gid     = blockIdx.x * blockDim.x + threadIdx.x;
    const int gstride = gridDim.x * blockDim.x;
    cg::grid_group grid = cg::this_grid();

    phase_prep(gid, gstride, W1, W2, W1p, W2p, (float4*)out);
    grid.sync();
    phase_node(smem, h, W1p, b1, Pa, Pb);
    grid.sync();
    phase_edge(smem, Pa, Pb, edge_index, coord_diff, edge_attr, edge_mask,
               W2p, W1, b2, W3, out);
    grid.sync();
    phase_fin(gid, gstride, coord, node_mask, out);
}

// ---------------- non-cooperative fallback kernels ----------------
__global__ __launch_bounds__(256) void k_prep(const float* W1, const float* W2,
                                              unsigned short* W1p, unsigned short* W2p,
                                              float4* outz) {
    phase_prep(blockIdx.x * blockDim.x + threadIdx.x, gridDim.x * blockDim.x,
               W1, W2, W1p, W2p, outz);
}
__global__ __launch_bounds__(256) void k_node(const float* h, const unsigned short* W1p,
                                              const float* b1, u32* Pa, u32* Pb) {
    __shared__ __align__(16) unsigned char smem[SMEM_BYTES];
    phase_node(smem, h, W1p, b1, Pa, Pb);
}
__global__ __launch_bounds__(256) void k_edge(const u32* Pa, const u32* Pb,
                                              const int* edge_index, const float* coord_diff,
                                              const float* edge_attr, const float* edge_mask,
                                              const unsigned short* W2p, const float* W1,
                                              const float* b2, const float* W3, float* agg) {
    __shared__ __align__(16) unsigned char smem[SMEM_BYTES];
    phase_edge(smem, Pa, Pb, edge_index, coord_diff, edge_attr, edge_mask,
               W2p, W1, b2, W3, agg);
}
__global__ void k_fin(const float* coord, const float* node_mask, float* out) {
    phase_fin(blockIdx.x * blockDim.x + threadIdx.x, gridDim.x * blockDim.x,
              coord, node_mask, out);
}

extern "C" void kernel_launch(void* const* d_in, const int* in_sizes, int n_in,
                              void* d_out, int out_size, void* d_ws, size_t ws_size,
                              hipStream_t stream) {
    const float* h          = (const float*)d_in[0];
    const float* coord      = (const float*)d_in[1];
    const int*   edge_index = (const int*)d_in[2];
    const float* coord_diff = (const float*)d_in[3];
    const float* edge_attr  = (const float*)d_in[5];
    const float* node_mask  = (const float*)d_in[6];
    const float* edge_mask  = (const float*)d_in[7];
    const float* W1         = (const float*)d_in[8];
    const float* b1         = (const float*)d_in[9];
    const float* W2         = (const float*)d_in[10];
    const float* b2         = (const float*)d_in[11];
    const float* W3         = (const float*)d_in[12];
    float* out = (float*)d_out;

    unsigned short* W1p = (unsigned short*)d_ws;
    unsigned short* W2p = W1p + N1;
    u32* Pa = (u32*)(W2p + N2);
    u32* Pb = Pa + (size_t)NN * 64;    // total ~25.7 MB (ws sufficiency proven R4-R6)

    // cooperative single-dispatch path
    int nb = 0;
    hipError_t qerr = hipOccupancyMaxActiveBlocksPerMultiprocessor(&nb, fused_all, 256, 0);
    if (qerr == hipSuccess && nb >= 1) {
        int G = nb * 256;               // MI355X: 256 CUs
        if (G > NT_EDGE) G = NT_EDGE;
        void* args[] = {(void*)&h, (void*)&edge_index, (void*)&coord, (void*)&coord_diff,
                        (void*)&edge_attr, (void*)&node_mask, (void*)&edge_mask,
                        (void*)&W1, (void*)&b1, (void*)&W2, (void*)&b2, (void*)&W3,
                        (void*)&W1p, (void*)&W2p, (void*)&Pa, (void*)&Pb, (void*)&out};
        hipError_t lerr = hipLaunchCooperativeKernel((const void*)fused_all, dim3(G),
                                                     dim3(256), args, 0, stream);
        if (lerr == hipSuccess) return;
    }

    // fallback: 4 sequential dispatches (R4-equivalent)
    int prep_items = N1 + N2 + OUTQ;
    k_prep<<<(prep_items + 255) / 256, 256, 0, stream>>>(W1, W2, W1p, W2p, (float4*)d_out);
    k_node<<<NT_NODE, 256, 0, stream>>>(h, W1p, b1, Pa, Pb);
    k_edge<<<NT_EDGE, 256, 0, stream>>>(Pa, Pb, edge_index, coord_diff, edge_attr, edge_mask,
                                        W2p, W1, b2, W3, out);
    k_fin<<<(NN + 255) / 256, 256, 0, stream>>>(coord, node_mask, out);
}

// Round 8
// 260.958 us; speedup vs baseline: 1.8032x; 1.8032x over previous
//
#include <hip/hip_runtime.h>
#include <hip/hip_bf16.h>

#define NN 50000
#define NE 800000
#define HID 128
#define ROWD 68           // x1 LDS pitch in dwords (17 mod 32 spread -> ~2-way banks)
#define APITCH 136        // node-gemm A-tile pitch in bf16 elems
#define N1 (32*128*8)     // W1p shorts
#define N2 (16*128*8)     // W2p shorts

typedef float f32x4 __attribute__((ext_vector_type(4)));
typedef short s16x8 __attribute__((ext_vector_type(8)));
typedef unsigned int u32;

__device__ __forceinline__ unsigned short f2bf(float x) {   // RNE
    u32 u = __float_as_uint(x);
    u32 r = (u + 0x7FFFu + ((u >> 16) & 1u)) >> 16;
    return (unsigned short)r;
}
__device__ __forceinline__ float silu_f(float v) {          // no IEEE divide
    float e = __expf(-v);
    return v * __builtin_amdgcn_rcpf(1.f + e);
}
__device__ __forceinline__ u32 pack2bf(float lo, float hi) {
    return __builtin_amdgcn_perm(__float_as_uint(hi), __float_as_uint(lo), 0x07060302u);
}
__device__ __forceinline__ u32 fuse_silu_pack(u32 a, u32 b, float ea, float wlo, float whi) {
    float xlo = __uint_as_float(a << 16) + __uint_as_float(b << 16) + ea * wlo;
    float xhi = __uint_as_float(a & 0xFFFF0000u) + __uint_as_float(b & 0xFFFF0000u) + ea * whi;
    return pack2bf(silu_f(xlo), silu_f(xhi));
}

// prep: W1p [32 kblk][128 n][8 kin] bf16; W2p sigma-K bf16 (verified R3-R7);
// and out init = coord * node_mask (replaces memset + lets finalize fold away).
__global__ void prep_kernel(const float* __restrict__ W1, const float* __restrict__ W2,
                            const float* __restrict__ coord, const float* __restrict__ node_mask,
                            unsigned short* __restrict__ W1p, unsigned short* __restrict__ W2p,
                            float* __restrict__ out) {
    int idx = blockIdx.x * blockDim.x + threadIdx.x;
    if (idx < N1) {
        int kblk = idx >> 10;
        int rem  = idx & 1023;
        int n    = rem >> 3;
        int kin  = rem & 7;
        W1p[idx] = f2bf(W1[(kblk * 8 + kin) * HID + n]);
    } else if (idx < N1 + N2) {
        int jj   = idx - N1;
        int kblk = jj >> 10;
        int rem  = jj & 1023;
        int n    = rem >> 3;
        int kin  = rem & 7;
        int p    = kblk * 8 + kin;
        int tt   = p >> 1;
        int srow = 32 * (tt >> 4) + (tt & 15) + 16 * (p & 1);
        W2p[jj] = f2bf(W2[srow * HID + n]);
    } else {
        int i = idx - (N1 + N2);
        if (i < NN) {
            float nm = node_mask[i];
            out[i * 3 + 0] = coord[i * 3 + 0] * nm;
            out[i * 3 + 1] = coord[i * 3 + 1] * nm;
            out[i * 3 + 2] = coord[i * 3 + 2] * nm;
        }
    }
}

// node_gemm: Pa[n] = h[n]@W1a + b1, Pb[n] = h[n]@W1b (sigma-paired bf16, 64 dw/row).
// Exact R4 structure (verified, edge-phase numerics absmax 0.0156).
__global__ __launch_bounds__(256) void node_gemm(const float* __restrict__ h,
                                                 const unsigned short* __restrict__ W1p,
                                                 const float* __restrict__ b1,
                                                 u32* __restrict__ Pa, u32* __restrict__ Pb) {
    __shared__ unsigned short s_a[64 * APITCH];   // 17408 B
    const int tid = threadIdx.x;
    const int m0  = blockIdx.x * 64;

    #pragma unroll
    for (int it = 0; it < 8; ++it) {
        int chunk = it * 256 + tid;
        int r  = chunk >> 5;
        int cc = chunk & 31;
        int row = m0 + r;
        float4 v = {0.f, 0.f, 0.f, 0.f};
        if (row < NN) v = *(const float4*)(h + (size_t)row * HID + cc * 4);
        uint2 pk;
        pk.x = ((u32)f2bf(v.x)) | ((u32)f2bf(v.y) << 16);
        pk.y = ((u32)f2bf(v.z)) | ((u32)f2bf(v.w) << 16);
        *(uint2*)&s_a[r * APITCH + cc * 4] = pk;
    }
    __syncthreads();

    const int lane = tid & 63;
    const int w    = tid >> 6;
    const int q    = lane >> 4;
    const int c16  = lane & 15;
    const int n0   = w * 32 + c16;

    f32x4 accA[4][2], accB[4][2];
    #pragma unroll
    for (int mt = 0; mt < 4; ++mt) {
        accA[mt][0] = f32x4{0.f,0.f,0.f,0.f}; accA[mt][1] = f32x4{0.f,0.f,0.f,0.f};
        accB[mt][0] = f32x4{0.f,0.f,0.f,0.f}; accB[mt][1] = f32x4{0.f,0.f,0.f,0.f};
    }
    #pragma unroll
    for (int ks = 0; ks < 4; ++ks) {
        s16x8 afr[4];
        #pragma unroll
        for (int mt = 0; mt < 4; ++mt)
            afr[mt] = *(const s16x8*)&s_a[(mt * 16 + c16) * APITCH + ks * 32 + q * 8];
        int ka = ks * 4 + q;
        int kb = 16 + ks * 4 + q;
        s16x8 ba0 = *(const s16x8*)(W1p + (size_t)(ka * HID + n0) * 8);
        s16x8 ba1 = *(const s16x8*)(W1p + (size_t)(ka * HID + n0 + 16) * 8);
        s16x8 bb0 = *(const s16x8*)(W1p + (size_t)(kb * HID + n0) * 8);
        s16x8 bb1 = *(const s16x8*)(W1p + (size_t)(kb * HID + n0 + 16) * 8);
        #pragma unroll
        for (int mt = 0; mt < 4; ++mt) {
            accA[mt][0] = __builtin_amdgcn_mfma_f32_16x16x32_bf16(afr[mt], ba0, accA[mt][0], 0, 0, 0);
            accA[mt][1] = __builtin_amdgcn_mfma_f32_16x16x32_bf16(afr[mt], ba1, accA[mt][1], 0, 0, 0);
            accB[mt][0] = __builtin_amdgcn_mfma_f32_16x16x32_bf16(afr[mt], bb0, accB[mt][0], 0, 0, 0);
            accB[mt][1] = __builtin_amdgcn_mfma_f32_16x16x32_bf16(afr[mt], bb1, accB[mt][1], 0, 0, 0);
        }
    }
    float b1lo = b1[n0], b1hi = b1[n0 + 16];
    const int d = w * 16 + c16;
    #pragma unroll
    for (int mt = 0; mt < 4; ++mt) {
        #pragma unroll
        for (int r = 0; r < 4; ++r) {
            int m = mt * 16 + q * 4 + r;     // C/D: col=lane&15, row=quad*4+reg
            int row = m0 + m;
            if (row < NN) {
                Pa[(size_t)row * 64 + d] = pack2bf(accA[mt][0][r] + b1lo, accA[mt][1][r] + b1hi);
                Pb[(size_t)row * 64 + d] = pack2bf(accB[mt][0][r], accB[mt][1][r]);
            }
        }
    }
}

// edge_kernel: 128 edges/block. ALL 16 Pa/Pb uint4 gathers issued up-front
// (16 outstanding vmem/thread vs R4's 8 -> 2x MLP during the latency stall),
// then two sequential 64-edge LDS tiles using R4's verified fuse/MFMA/phi code.
// finalize folded into the atomics: agg-add includes 0.01 * node_mask[r].
__global__ __launch_bounds__(256) void edge_kernel(
        const u32* __restrict__ Pa, const u32* __restrict__ Pb,
        const int* __restrict__ edge_index,
        const float* __restrict__ coord_diff, const float* __restrict__ edge_attr,
        const float* __restrict__ edge_mask, const float* __restrict__ node_mask,
        const unsigned short* __restrict__ W2p, const float* __restrict__ W1,
        const float* __restrict__ b2, const float* __restrict__ W3,
        float* __restrict__ agg) {
    __shared__ u32   s_x1[64 * ROWD];   // 17408 B
    __shared__ float s_phi[256];        // 1024 B

    const int tid  = threadIdx.x;
    const int lane = tid & 63;
    const int w    = tid >> 6;
    const int q    = lane >> 4;
    const int c16  = lane & 15;
    const int n0   = w * 32 + c16;
    const int e0   = blockIdx.x * 128;
    const int c    = tid & 15;          // dword group
    const int rs   = tid >> 4;          // row-sub 0..15

    // fuse constants for dword group c (sigma col map, verified R4)
    const float* W1r = W1 + 256 * HID;
    float w1rlo[4], w1rhi[4];
    #pragma unroll
    for (int i = 0; i < 4; ++i) {
        int dd = c * 4 + i;
        int cl = 32 * (dd >> 4) + (dd & 15);
        w1rlo[i] = W1r[cl];
        w1rhi[i] = W1r[cl + 16];
    }
    const float b2lo = b2[n0], b2hi = b2[n0 + 16];
    const float w3lo = W3[n0], w3hi = W3[n0 + 16];

    // ---- up-front gather for BOTH 64-edge tiles: 16 uint4 in flight ----
    uint4 pa[8], pb[8];
    float eas[8];
    #pragma unroll
    for (int it = 0; it < 8; ++it) {
        int e  = e0 + it * 16 + rs;
        int ri = edge_index[e];
        int ci = edge_index[NE + e];
        eas[it] = edge_attr[e];
        pa[it] = *(const uint4*)(Pa + (size_t)ri * 64 + c * 4);
        pb[it] = *(const uint4*)(Pb + (size_t)ci * 64 + c * 4);
    }

    #pragma unroll
    for (int half = 0; half < 2; ++half) {
        // fuse + write x1 tile (rows 0..63 local)
        #pragma unroll
        for (int it2 = 0; it2 < 4; ++it2) {
            int it = half * 4 + it2;
            int m  = it2 * 16 + rs;
            uint4 o;
            o.x = fuse_silu_pack(pa[it].x, pb[it].x, eas[it], w1rlo[0], w1rhi[0]);
            o.y = fuse_silu_pack(pa[it].y, pb[it].y, eas[it], w1rlo[1], w1rhi[1]);
            o.z = fuse_silu_pack(pa[it].z, pb[it].z, eas[it], w1rlo[2], w1rhi[2]);
            o.w = fuse_silu_pack(pa[it].w, pb[it].w, eas[it], w1rlo[3], w1rhi[3]);
            *(uint4*)&s_x1[m * ROWD + c * 4] = o;
        }
        __syncthreads();

        // layer 2: [64,128] @ W2p (sigma-K)
        f32x4 acc2[4][2];
        #pragma unroll
        for (int mt = 0; mt < 4; ++mt) {
            acc2[mt][0] = f32x4{0.f,0.f,0.f,0.f};
            acc2[mt][1] = f32x4{0.f,0.f,0.f,0.f};
        }
        #pragma unroll
        for (int ks = 0; ks < 4; ++ks) {
            int kblk = ks * 4 + q;
            s16x8 b0  = *(const s16x8*)(W2p + (size_t)(kblk * HID + n0) * 8);
            s16x8 b1f = *(const s16x8*)(W2p + (size_t)(kblk * HID + n0 + 16) * 8);
            #pragma unroll
            for (int mt = 0; mt < 4; ++mt) {
                s16x8 afr = *(const s16x8*)&s_x1[(mt * 16 + c16) * ROWD + ks * 16 + q * 4];
                acc2[mt][0] = __builtin_amdgcn_mfma_f32_16x16x32_bf16(afr, b0,  acc2[mt][0], 0, 0, 0);
                acc2[mt][1] = __builtin_amdgcn_mfma_f32_16x16x32_bf16(afr, b1f, acc2[mt][1], 0, 0, 0);
            }
        }

        // layer 3: phi = sum_n silu(x2+b2)*W3
        #pragma unroll
        for (int mt = 0; mt < 4; ++mt) {
            float pr[4];
            #pragma unroll
            for (int r = 0; r < 4; ++r) {
                float s0 = silu_f(acc2[mt][0][r] + b2lo);
                float s1 = silu_f(acc2[mt][1][r] + b2hi);
                pr[r] = fmaf(s0, w3lo, s1 * w3hi);
            }
            #pragma unroll
            for (int off = 8; off >= 1; off >>= 1) {
                #pragma unroll
                for (int r = 0; r < 4; ++r) pr[r] += __shfl_xor(pr[r], off);
            }
            if (c16 == 0) {
                #pragma unroll
                for (int r = 0; r < 4; ++r)
                    s_phi[(mt * 16 + q * 4 + r) * 4 + w] = pr[r];
            }
        }
        __syncthreads();

        // epilogue: atomics with folded 0.01 * node_mask
        if (tid < 64) {
            int e = e0 + half * 64 + tid;
            float phi = s_phi[tid * 4 + 0] + s_phi[tid * 4 + 1]
                      + s_phi[tid * 4 + 2] + s_phi[tid * 4 + 3];
            int r = edge_index[e];
            float scale = phi * edge_mask[e] * 0.01f * node_mask[r];
            atomicAdd(&agg[r * 3 + 0], coord_diff[e * 3 + 0] * scale);
            atomicAdd(&agg[r * 3 + 1], coord_diff[e * 3 + 1] * scale);
            atomicAdd(&agg[r * 3 + 2], coord_diff[e * 3 + 2] * scale);
        }
        // no extra barrier: next half's s_x1 writes don't touch s_phi, and
        // s_phi re-stores happen only after the next __syncthreads().
    }
}

extern "C" void kernel_launch(void* const* d_in, const int* in_sizes, int n_in,
                              void* d_out, int out_size, void* d_ws, size_t ws_size,
                              hipStream_t stream) {
    const float* h          = (const float*)d_in[0];
    const float* coord      = (const float*)d_in[1];
    const int*   edge_index = (const int*)d_in[2];
    const float* coord_diff = (const float*)d_in[3];
    // d_in[4] coord_cross: unused
    const float* edge_attr  = (const float*)d_in[5];
    const float* node_mask  = (const float*)d_in[6];
    const float* edge_mask  = (const float*)d_in[7];
    const float* W1         = (const float*)d_in[8];
    const float* b1         = (const float*)d_in[9];
    const float* W2         = (const float*)d_in[10];
    const float* b2         = (const float*)d_in[11];
    const float* W3         = (const float*)d_in[12];
    float* out = (float*)d_out;

    unsigned short* W1p = (unsigned short*)d_ws;
    unsigned short* W2p = W1p + N1;
    u32* Pa = (u32*)(W2p + N2);
    u32* Pb = Pa + (size_t)NN * 64;    // total ~25.7 MB (ws sufficiency proven R4-R7)

    // 3 dispatches: prep (weights + out init) -> node GEMM -> edges
    const int prep_items = N1 + N2 + NN;
    prep_kernel<<<(prep_items + 255) / 256, 256, 0, stream>>>(W1, W2, coord, node_mask,
                                                              W1p, W2p, out);
    node_gemm<<<(NN + 63) / 64, 256, 0, stream>>>(h, W1p, b1, Pa, Pb);
    edge_kernel<<<NE / 128, 256, 0, stream>>>(Pa, Pb, edge_index, coord_diff, edge_attr,
                                              edge_mask, node_mask, W2p, W1, b2, W3, out);
}